// Round 11
// baseline (431.884 us; speedup 1.0000x reference)
//
#include <hip/hip_runtime.h>
#include <math.h>
#include <stdint.h>

// GlobalAttentionPool: score = segsum_edges(x[src].W_rel)[dst] + x.W_root (+b_rel,
// cancels in softmax); att = per-graph softmax; out = segsum(x*att).
//
// R2: scattered global atomics never coalesce (~18.6G/s) -> minimize COUNT.
// R8: LDS int fixed-point ds_add_u32. R9/R11: staged LDS->linear sort writes.
// R12: 2-barrier scan + int4 loads. R13 (FALSIFIED): cursor replication null.
// R14/R15 (MEASUREMENT): pad-spin attribution (~100MHz, additive): edge_sort
//     ~16us, pool ~20us, node_prep ~5, finalize ~1; residual ~70us = harness
//     re-poison fill (42.5us/256MiB in-window) + memset train + gaps.
// R16: fused bucket_accum+pool: 125 -> 118.5.
// R17-R20: four pool theories dead (interleave understood at R21).
// R21 (ABLATION): Phase C == 100% of bucket_pool; Little's law -> <1
//     outstanding x-load/wave: per-iter LDS+global interleave makes merged
//     s_waitcnt serialize loads.
// R22 (WIN, confirmed): batch 32 x-loads before LDS reads: 117.6 -> 109.5
//     (bucket_pool 18.5 -> ~10). Ledger: node_prep 5 (BW-floor), edge_sort
//     16 (model 4-5: 10x per-block critical-path gap UNEXPLAINED),
//     bucket_pool 10, finalize 1, gaps ~5, harness ~70.
// R23 (ABLATION ROUND): edge_sort pass split, same instrument that cracked
//     bucket_pool. Four scratch-target variants (cursor2/sorted2) after
//     finalize, distinct pads (54.5/64.4/74.3/84.2us):
//       MODE1 A-only | MODE2 +scan/cursor | MODE3 +scatter | MODE0 full.
//     Real pipeline IDENTICAL to R22 (109.5us config).
//     Predict dur ~425-445. Decision: tA>=10 -> Pass A; dAB>=5 -> scan;
//     dABC>=5 -> scatter conflicts; dD>=5 -> Pass D; all small -> dispatch
//     effect -> mega-fusion.

#define H 64
#define TILE 4096           // edges per sort tile
#define NTHR_S 1024
#define EPT (TILE / NTHR_S) // 4
#define BUCKET_SZ 256       // nodes per bucket
#define MAX_NB 400          // >= ceil(100000/256) = 391
#define NREP 8              // cursor replicas (== #XCDs)
#define SUBCAP 768          // slots per (bucket, replica); mean ~513
#define CAP (NREP * SUBCAP) // 6144 slots per bucket
#define PSCALE 16384.0f     // 2^14 fixed-point scale
#define INV_PSCALE 6.103515625e-05f

__device__ __forceinline__ void spin_pad(unsigned long long ticks)
{
    unsigned long long t0 = __builtin_amdgcn_s_memrealtime();
    while (__builtin_amdgcn_s_memrealtime() - t0 < ticks) { }
}

// K1: per-node dots p = x.W_rel, r = x.W_root (4 threads/node, float4 loads);
// zero num[]/z[]; init cursor[2*nb*NREP] (real + scratch replica sets).
__global__ __launch_bounds__(256) void node_prep(
    const float4* __restrict__ x4, const float4* __restrict__ W_rel4,
    const float4* __restrict__ W_root4,
    float* __restrict__ p, float* __restrict__ r,
    float* __restrict__ num, float* __restrict__ z,
    unsigned int* __restrict__ cursor,
    int n_nodes, int num_elems, int n_graphs, int nb)
{
    int gid = (int)(blockIdx.x * blockDim.x + threadIdx.x);
    if (gid < num_elems) num[gid] = 0.0f;
    else if (gid < num_elems + n_graphs) z[gid - num_elems] = 0.0f;
    else if (gid < num_elems + n_graphs + 2 * nb * NREP) {
        int idx = gid - num_elems - n_graphs;    // covers cursor AND cursor2
        int rep = (idx / nb) % NREP;
        int k   = idx % nb;
        cursor[idx] = (unsigned int)(k * CAP + rep * SUBCAP);
    }

    int node = blockIdx.x * 64 + (threadIdx.x >> 2);
    int q    = threadIdx.x & 3;
    if (node >= n_nodes) return;

    float pv = 0.0f, rv = 0.0f;
    #pragma unroll
    for (int kk = 0; kk < 4; ++kk) {
        float4 v  = x4[node * 16 + kk * 4 + q];
        float4 wr = W_rel4[kk * 4 + q];
        float4 wo = W_root4[kk * 4 + q];
        pv += v.x * wr.x + v.y * wr.y + v.z * wr.z + v.w * wr.w;
        rv += v.x * wo.x + v.y * wo.y + v.z * wo.z + v.w * wo.w;
    }
    pv += __shfl_xor(pv, 1, 64); pv += __shfl_xor(pv, 2, 64);
    rv += __shfl_xor(rv, 1, 64); rv += __shfl_xor(rv, 2, 64);
    if (q == 0) { p[node] = pv; r[node] = rv; }
}

// K2 template: per-tile bucket partition. MODE 0=full, 1=Pass A only,
// 2=A+B (scan+cursor), 3=A+B+C (+LDS scatter, linear readback).
// Keepalive global stores in each truncated mode prevent DCE (rule #17).
// pad_ticks: visibility pad (0 for the real pipeline instance).
template<int MODE>
__global__ __launch_bounds__(NTHR_S) void edge_sort_t(
    const int* __restrict__ src, const int* __restrict__ dst,
    const float* __restrict__ p,
    unsigned int* __restrict__ cursor, unsigned int* __restrict__ sorted_g,
    int n_edges, int nb, unsigned long long pad_ticks)
{
    __shared__ unsigned int hist[MAX_NB];
    __shared__ unsigned int offs[MAX_NB];
    __shared__ unsigned int gbase[MAX_NB];
    __shared__ unsigned int wtot[8];
    __shared__ unsigned int svals[TILE];          // 16 KB payloads
    __shared__ unsigned short sbid[TILE];         // 8 KB bucket ids

    int b = blockIdx.x;
    int rep = b & (NREP - 1);                     // == XCD id (round-robin)
    int base = b * TILE;
    int tile_n = min(TILE, n_edges - base);
    int tid = threadIdx.x;

    if (tid < nb) hist[tid] = 0;
    __syncthreads();

    // ---- Pass A: vectorized loads + count/slot ----
    unsigned int dd[EPT]; int ss[EPT];
    float pv[EPT];
    unsigned int bk[EPT], pk[EPT], slot[EPT];

    int j0 = tid * EPT;                    // 4 consecutive edges per thread
    if (j0 + EPT <= tile_n) {
        int4 s4 = *(const int4*)(src + base + j0);
        int4 d4 = *(const int4*)(dst + base + j0);
        ss[0] = s4.x; ss[1] = s4.y; ss[2] = s4.z; ss[3] = s4.w;
        dd[0] = (unsigned int)d4.x; dd[1] = (unsigned int)d4.y;
        dd[2] = (unsigned int)d4.z; dd[3] = (unsigned int)d4.w;
    } else {
        #pragma unroll
        for (int u = 0; u < EPT; ++u) {
            int j = j0 + u;
            if (j < tile_n) { ss[u] = src[base + j];
                              dd[u] = (unsigned int)dst[base + j]; }
            else dd[u] = 0xFFFFFFFFu;
        }
    }
    #pragma unroll
    for (int u = 0; u < EPT; ++u)          // batched p gathers (ILP)
        if (dd[u] != 0xFFFFFFFFu) pv[u] = p[ss[u]];
    #pragma unroll
    for (int u = 0; u < EPT; ++u) {
        if (dd[u] != 0xFFFFFFFFu) {
            bk[u] = dd[u] >> 8;
            int q = (int)__float2int_rn(pv[u] * PSCALE);
            q = max(-8388607, min(8388607, q));          // 24-bit clamp
            pk[u] = ((unsigned int)q << 8) | (dd[u] & 255u);
            slot[u] = atomicAdd(&hist[bk[u]], 1u);
        }
    }
    __syncthreads();

    if (MODE == 1) {                       // A-only: keepalive then pad
        unsigned int ka = 0;
        #pragma unroll
        for (int u = 0; u < EPT; ++u) ka ^= pk[u] + slot[u];
        sorted_g[base + tid] = ka;                        // junk region OK
        if (tid < nb) sorted_g[base + NTHR_S + tid] = hist[tid];
        spin_pad(pad_ticks); return;
    }

    // ---- Pass B: 2-barrier scan ----
    int wv = tid >> 6, ln = tid & 63;
    unsigned int v = 0, xs = 0;
    if (wv < 7) {
        int bin = wv * 64 + ln;                    // 0..447 covers nb<=400
        v = (bin < nb) ? hist[bin] : 0;
        xs = v;                                     // inclusive shuffle scan
        #pragma unroll
        for (int off = 1; off < 64; off <<= 1) {
            unsigned int y = __shfl_up(xs, off, 64);
            if (ln >= off) xs += y;
        }
        if (ln == 63) wtot[wv] = xs;
    }
    __syncthreads();
    if (wv < 7) {
        int bin = wv * 64 + ln;
        unsigned int pre = 0;
        #pragma unroll
        for (int w2 = 0; w2 < 7; ++w2)
            pre += (w2 < wv) ? wtot[w2] : 0u;
        if (bin < nb) {
            offs[bin]  = pre + xs - v;             // exclusive prefix
            gbase[bin] = v ? atomicAdd(&cursor[rep * nb + bin], v) : 0u;
        }
    }
    __syncthreads();

    if (MODE == 2) {                       // A+B: keepalive then pad
        if (tid < nb)
            sorted_g[base + tid] = offs[tid] + gbase[tid] * 2654435761u;
        spin_pad(pad_ticks); return;
    }

    // ---- Pass C: LDS scatter into run order ----
    #pragma unroll
    for (int u = 0; u < EPT; ++u) {
        if (dd[u] != 0xFFFFFFFFu) {
            unsigned int pos = offs[bk[u]] + slot[u];
            svals[pos] = pk[u];
            sbid[pos]  = (unsigned short)bk[u];
        }
    }
    __syncthreads();

    if (MODE == 3) {                       // A+B+C: linear readback write
        for (int j = tid; j < tile_n; j += NTHR_S)
            sorted_g[base + j] = svals[j] + (unsigned int)sbid[j];
        spin_pad(pad_ticks); return;
    }

    // ---- Pass D: linear write (consecutive j -> consecutive global) ----
    for (int j = tid; j < tile_n; j += NTHR_S) {
        unsigned int bb = sbid[j];
        unsigned int gi = gbase[bb] + ((unsigned int)j - offs[bb]);
        unsigned int lim = bb * (unsigned int)CAP
                         + (unsigned int)(rep + 1) * SUBCAP;
        if (gi < lim)                               // sub-region overflow guard
            sorted_g[gi] = svals[j];
    }
    if (pad_ticks) spin_pad(pad_ticks);
}

// K3 (fused bucket_accum + pool), R22 form (batched C1 loads).
__global__ __launch_bounds__(512) void bucket_pool(
    const unsigned int* __restrict__ sorted_g,
    const unsigned int* __restrict__ cursor,
    const float* __restrict__ r,
    const float* __restrict__ x,
    const int* __restrict__ batch,
    float* __restrict__ num, float* __restrict__ z,
    int n_nodes, int nb)
{
    __shared__ int acc[BUCKET_SZ];
    __shared__ float e_lds[BUCKET_SZ];
    __shared__ int g_lds[BUCKET_SZ];
    __shared__ unsigned int cnts[NREP];
    __shared__ float pnum[2 * NREP][H];           // 4 KB segment partials
    __shared__ float pz[2 * NREP];
    __shared__ int   sgid[2 * NREP];

    int k = blockIdx.x;
    int tid = threadIdx.x;
    int node0 = k * BUCKET_SZ;

    if (tid < BUCKET_SZ) acc[tid] = 0;
    else {
        int t2 = tid - BUCKET_SZ;                 // 0..255
        int node = node0 + t2;
        g_lds[t2] = (node < n_nodes) ? batch[node] : -1;
    }
    if (tid < NREP) {
        unsigned int begr = (unsigned int)(k * CAP + tid * SUBCAP);
        cnts[tid] = min(cursor[tid * nb + k] - begr, (unsigned int)SUBCAP);
    }
    if (tid < 2 * NREP) sgid[tid] = -1;
    __syncthreads();

    // ---- Phase A: wave w accumulates replica w ----
    {
        int wv = tid >> 6, ln = tid & 63;         // wv == replica id
        unsigned int beg = (unsigned int)(k * CAP + wv * SUBCAP);
        unsigned int cnt = cnts[wv];
        unsigned int n4  = cnt & ~3u;
        for (unsigned int j = ln * 4; j < n4; j += 256) {
            uint4 v = *(const uint4*)(sorted_g + beg + j);
            atomicAdd(&acc[v.x & 255u], (int)v.x >> 8);
            atomicAdd(&acc[v.y & 255u], (int)v.y >> 8);
            atomicAdd(&acc[v.z & 255u], (int)v.z >> 8);
            atomicAdd(&acc[v.w & 255u], (int)v.w >> 8);
        }
        for (unsigned int j = n4 + ln; j < cnt; j += 64) {
            unsigned int v = sorted_g[beg + j];
            atomicAdd(&acc[v & 255u], (int)v >> 8);
        }
    }
    __syncthreads();

    // ---- Phase B: e = exp(score) in LDS ----
    if (tid < BUCKET_SZ) {
        int node = node0 + tid;
        e_lds[tid] = (node < n_nodes)
                   ? __expf((float)acc[tid] * INV_PSCALE + r[node]) : 0.0f;
    }
    __syncthreads();

    // ---- Phase C1: batched loads, then accumulate ----
    int wid = tid >> 6, lane = tid & 63;
    int l0 = wid * 32;
    int row0 = node0 + l0;
    int s0 = wid * 2;
    if (row0 < n_nodes) {
        int rend = min(row0 + 32, n_nodes);
        int gF = g_lds[l0];
        int gL = g_lds[rend - 1 - node0];
        float sA = 0.0f, sB = 0.0f, zA = 0.0f, zB = 0.0f;

        if (rend - row0 == 32) {
            float xv[32];
            const float* xp = x + (size_t)row0 * H + lane;
            #pragma unroll
            for (int u = 0; u < 32; ++u)
                xv[u] = xp[u * H];
            #pragma unroll
            for (int u = 0; u < 32; ++u) {
                int li = l0 + u;
                int g = g_lds[li];                // wave-uniform
                float e = e_lds[li];
                float v = xv[u] * e;
                if (g == gF)      { sA += v; zA += e; }
                else if (g == gL) { sB += v; zB += e; }
                else {
                    unsafeAtomicAdd(&num[g * H + lane], v);
                    if (lane == 0) unsafeAtomicAdd(&z[g], e);
                }
            }
        } else {
            for (int i = row0; i < rend; ++i) {
                int li = i - node0;
                int g = g_lds[li];
                float e = e_lds[li];
                float v = x[(size_t)i * H + lane] * e;
                if (g == gF)      { sA += v; zA += e; }
                else if (g == gL) { sB += v; zB += e; }
                else {
                    unsafeAtomicAdd(&num[g * H + lane], v);
                    if (lane == 0) unsafeAtomicAdd(&z[g], e);
                }
            }
        }
        pnum[s0][lane] = sA;
        if (lane == 0) { sgid[s0] = gF; pz[s0] = zA; }
        if (gL != gF) {
            pnum[s0 + 1][lane] = sB;
            if (lane == 0) { sgid[s0 + 1] = gL; pz[s0 + 1] = zB; }
        }
    }
    __syncthreads();

    // ---- Phase C2: wave 0 merges ordered segments -> per-graph atomics ----
    if (wid == 0) {
        float run = 0.0f, runz = 0.0f; int cur = -1;
        for (int s = 0; s < 2 * NREP; ++s) {
            int id = sgid[s];                     // non-decreasing over s
            if (id < 0) continue;
            float v  = pnum[s][lane];
            float zv = pz[s];
            if (id != cur) {
                if (cur >= 0) {
                    unsafeAtomicAdd(&num[cur * H + lane], run);
                    if (lane == 0) unsafeAtomicAdd(&z[cur], runz);
                }
                cur = id; run = v; runz = zv;
            } else { run += v; runz += zv; }
        }
        if (cur >= 0) {
            unsafeAtomicAdd(&num[cur * H + lane], run);
            if (lane == 0) unsafeAtomicAdd(&z[cur], runz);
        }
    }
}

// K4: out = num / z (plain stores; empty graphs -> 0).
__global__ __launch_bounds__(256) void finalize(
    const float* __restrict__ num, const float* __restrict__ z,
    float* __restrict__ out, int num_elems)
{
    int i = (int)(blockIdx.x * blockDim.x + threadIdx.x);
    if (i >= num_elems) return;
    float zz = z[i >> 6];
    out[i] = (zz != 0.0f) ? num[i] / zz : 0.0f;
}

extern "C" void kernel_launch(void* const* d_in, const int* in_sizes, int n_in,
                              void* d_out, int out_size, void* d_ws, size_t ws_size,
                              hipStream_t stream)
{
    const float* x      = (const float*)d_in[0];
    const int*   eidx   = (const int*)d_in[1];   // [2, E] int32
    const int*   batch  = (const int*)d_in[2];   // [N] int32, sorted
    const float* W_rel  = (const float*)d_in[3];
    // d_in[4] = b_rel: cancels in softmax
    const float* W_root = (const float*)d_in[5];
    float* out = (float*)d_out;

    const int n_nodes  = in_sizes[0] / H;          // 100000
    const int n_edges  = in_sizes[1] / 2;          // 1600000
    const int n_graphs = out_size / H;             // 512
    const int nb     = (n_nodes + BUCKET_SZ - 1) / BUCKET_SZ;   // 391
    const int ntiles = (n_edges + TILE - 1) / TILE;             // 391

    const int* src = eidx;
    const int* dst = eidx + n_edges;

    // workspace: p[N] r[N] z[G] num[G*H] cursor[2*nb*NREP] | sorted_g | sorted2
    float* p     = (float*)d_ws;
    float* r     = p + n_nodes;
    float* z     = r + n_nodes;
    float* num   = z + n_graphs;
    unsigned int* cursor  = (unsigned int*)(num + out_size);
    unsigned int* cursor2 = cursor + nb * NREP;
    uintptr_t raw = (uintptr_t)(cursor2 + nb * NREP);
    unsigned int* sorted_g = (unsigned int*)((raw + 15) & ~(uintptr_t)15);
    unsigned int* sorted2  = sorted_g + (size_t)nb * CAP;

    int np_blocks = (n_nodes + 63) / 64;   // 1563; also covers zero-init range
    node_prep<<<np_blocks, 256, 0, stream>>>(
        (const float4*)x, (const float4*)W_rel, (const float4*)W_root,
        p, r, num, z, cursor, n_nodes, out_size, n_graphs, nb);
    edge_sort_t<0><<<ntiles, NTHR_S, 0, stream>>>(
        src, dst, p, cursor, sorted_g, n_edges, nb, 0ULL);      // real
    bucket_pool<<<nb, 512, 0, stream>>>(sorted_g, cursor, r, x, batch,
                                        num, z, n_nodes, nb);
    finalize<<<(out_size + 255) / 256, 256, 0, stream>>>(num, z, out, out_size);

    // ---- R23 ablation probes (scratch cursor2/sorted2, distinct pads) ----
    edge_sort_t<1><<<ntiles, NTHR_S, 0, stream>>>(
        src, dst, p, cursor2, sorted2, n_edges, nb, 5500ULL);   // A      ~54.5+
    edge_sort_t<2><<<ntiles, NTHR_S, 0, stream>>>(
        src, dst, p, cursor2, sorted2, n_edges, nb, 6500ULL);   // A+B    ~64.4+
    edge_sort_t<3><<<ntiles, NTHR_S, 0, stream>>>(
        src, dst, p, cursor2, sorted2, n_edges, nb, 7500ULL);   // A+B+C  ~74.3+
    edge_sort_t<0><<<ntiles, NTHR_S, 0, stream>>>(
        src, dst, p, cursor2, sorted2, n_edges, nb, 8500ULL);   // full   ~84.2+
}

// Round 12
// 217.531 us; speedup vs baseline: 1.9854x; 1.9854x over previous
//
#include <hip/hip_runtime.h>
#include <hip/hip_cooperative_groups.h>
#include <math.h>
#include <stdint.h>

namespace cg = cooperative_groups;

// GlobalAttentionPool: score = segsum_edges(x[src].W_rel)[dst] + x.W_root (+b_rel,
// cancels in softmax); att = per-graph softmax; out = segsum(x*att).
//
// R2: scattered global atomics never coalesce (~18.6G/s) -> minimize COUNT.
// R8: LDS int fixed-point ds_add_u32. R9/R11: staged LDS->linear sort writes.
// R12: 2-barrier scan + int4 loads. R13: cursor replication null.
// R14/R15: pad-spin attribution (~100MHz wall clock, pads additive).
// R16: fused bucket_accum+pool: 125 -> 118.5.
// R17-R20: four pool theories dead; R21 ablation -> Phase C 100%, <1
//     outstanding x-load/wave (merged s_waitcnt serializes interleaved
//     LDS+global). R22 (WIN): batch 32 x-loads first: 117.6 -> 109.5.
// R23 (ABLATION): edge_sort sum-constraint -> Pass A ~= 7us (= its floor:
//     12.8MB poison-cold index streams ~4us + 1.6M scattered p-gather
//     line-requests ~2.6us @ ~1 line/cy/CU); other passes ~3us each.
//     tFull = 15.8 re-confirmed. No mystery left inside kernels.
// R24 (this round): ledger = kernels ~32us (each at BW/request floors) +
//     harness fill/memsets ~70us + INTER-DISPATCH GAPS ~8-12us. Last lever:
//     ONE cooperative kernel (grid.sync between phases; guide-blessed).
//     256 blocks x 1024 thr = 1 block/CU co-resident (LDS 41KB, VGPR<<128);
//     tiles/buckets grid-stride; bucket phase = R21's verified 16-wave port
//     (RPW=2, RW=16, NSEG=32) + R22 batched loads.
//     Predict 109.5 -> ~97-103. Pre-commit: error -> revert; >=107 ->
//     floors + harness dominate -> ROOFLINE next round.

#define H 64
#define TILE 4096
#define BUCKET_SZ 256
#define MAX_NB 400          // >= nb = 391
#define NREP 8
#define SUBCAP 768
#define CAP (NREP * SUBCAP) // 6144
#define PSCALE 16384.0f
#define INV_PSCALE 6.103515625e-05f
#define NBLK 256
#define NTHR 1024
#define EPT (TILE / NTHR)   // 4
#define NSEG 32             // 16 waves x 2 segments

__global__ __launch_bounds__(NTHR) void fused_pipeline(
    const float4* __restrict__ x4, const float4* __restrict__ W_rel4,
    const float4* __restrict__ W_root4,
    const int* __restrict__ src, const int* __restrict__ dst,
    const int* __restrict__ batch,
    float* __restrict__ p, float* __restrict__ r,
    float* __restrict__ z, float* __restrict__ num,
    unsigned int* __restrict__ cursor, unsigned int* __restrict__ sorted_g,
    float* __restrict__ out,
    int n_nodes, int n_edges, int n_graphs, int nb, int ntiles, int out_size)
{
    cg::grid_group grid = cg::this_grid();

    // ---- LDS (union of all phases; 1 block/CU so ~41KB is fine) ----
    __shared__ unsigned int hist[MAX_NB];
    __shared__ unsigned int offs[MAX_NB];
    __shared__ unsigned int gbase[MAX_NB];
    __shared__ unsigned int wtot[8];
    __shared__ unsigned int svals[TILE];          // 16 KB
    __shared__ unsigned short sbid[TILE];         // 8 KB
    __shared__ int acc[BUCKET_SZ];
    __shared__ float e_lds[BUCKET_SZ];
    __shared__ int g_lds[BUCKET_SZ];
    __shared__ unsigned int cnts[NREP];
    __shared__ float pnum[NSEG][H];               // 8 KB
    __shared__ float pz[NSEG];
    __shared__ int   sgid[NSEG];

    int tid = threadIdx.x, bid = blockIdx.x;
    int gt  = bid * NTHR + tid;
    int wid = tid >> 6, lane = tid & 63;

    // ================= Phase 1: init + node dots =================
    if (gt < out_size) num[gt] = 0.0f;
    else if (gt < out_size + n_graphs) z[gt - out_size] = 0.0f;
    else if (gt < out_size + n_graphs + nb * NREP) {
        int idx = gt - out_size - n_graphs;       // rep*nb + k
        int rep = idx / nb;
        int k   = idx - rep * nb;
        cursor[idx] = (unsigned int)(k * CAP + rep * SUBCAP);
    }

    {
        int q = gt & 3;
        for (int node = (gt >> 2); node < n_nodes; node += (NBLK * NTHR) / 4) {
            float pv = 0.0f, rv = 0.0f;
            #pragma unroll
            for (int kk = 0; kk < 4; ++kk) {
                float4 v  = x4[node * 16 + kk * 4 + q];
                float4 wr = W_rel4[kk * 4 + q];
                float4 wo = W_root4[kk * 4 + q];
                pv += v.x * wr.x + v.y * wr.y + v.z * wr.z + v.w * wr.w;
                rv += v.x * wo.x + v.y * wo.y + v.z * wo.z + v.w * wo.w;
            }
            pv += __shfl_xor(pv, 1, 64); pv += __shfl_xor(pv, 2, 64);
            rv += __shfl_xor(rv, 1, 64); rv += __shfl_xor(rv, 2, 64);
            if (q == 0) { p[node] = pv; r[node] = rv; }
        }
    }
    grid.sync();

    // ================= Phase 2: edge sort (grid-stride tiles) =================
    for (int t = bid; t < ntiles; t += NBLK) {
        int rep = t & (NREP - 1);
        int base = t * TILE;
        int tile_n = min(TILE, n_edges - base);

        if (tid < nb) hist[tid] = 0;
        __syncthreads();

        // Pass A: vectorized loads + count/slot
        unsigned int dd[EPT]; int ss[EPT];
        float pv[EPT];
        unsigned int bk[EPT], pk[EPT], slot[EPT];

        int j0 = tid * EPT;
        if (j0 + EPT <= tile_n) {
            int4 s4 = *(const int4*)(src + base + j0);
            int4 d4 = *(const int4*)(dst + base + j0);
            ss[0] = s4.x; ss[1] = s4.y; ss[2] = s4.z; ss[3] = s4.w;
            dd[0] = (unsigned int)d4.x; dd[1] = (unsigned int)d4.y;
            dd[2] = (unsigned int)d4.z; dd[3] = (unsigned int)d4.w;
        } else {
            #pragma unroll
            for (int u = 0; u < EPT; ++u) {
                int j = j0 + u;
                if (j < tile_n) { ss[u] = src[base + j];
                                  dd[u] = (unsigned int)dst[base + j]; }
                else dd[u] = 0xFFFFFFFFu;
            }
        }
        #pragma unroll
        for (int u = 0; u < EPT; ++u)
            if (dd[u] != 0xFFFFFFFFu) pv[u] = p[ss[u]];
        #pragma unroll
        for (int u = 0; u < EPT; ++u) {
            if (dd[u] != 0xFFFFFFFFu) {
                bk[u] = dd[u] >> 8;
                int qv = (int)__float2int_rn(pv[u] * PSCALE);
                qv = max(-8388607, min(8388607, qv));
                pk[u] = ((unsigned int)qv << 8) | (dd[u] & 255u);
                slot[u] = atomicAdd(&hist[bk[u]], 1u);
            }
        }
        __syncthreads();

        // Pass B: 2-barrier scan (waves 0..6 cover 448 >= nb bins)
        unsigned int v = 0, xs = 0;
        if (wid < 7) {
            int bin = wid * 64 + lane;
            v = (bin < nb) ? hist[bin] : 0;
            xs = v;
            #pragma unroll
            for (int off = 1; off < 64; off <<= 1) {
                unsigned int y = __shfl_up(xs, off, 64);
                if (lane >= off) xs += y;
            }
            if (lane == 63) wtot[wid] = xs;
        }
        __syncthreads();
        if (wid < 7) {
            int bin = wid * 64 + lane;
            unsigned int pre = 0;
            #pragma unroll
            for (int w2 = 0; w2 < 7; ++w2)
                pre += (w2 < wid) ? wtot[w2] : 0u;
            if (bin < nb) {
                offs[bin]  = pre + xs - v;
                gbase[bin] = v ? atomicAdd(&cursor[rep * nb + bin], v) : 0u;
            }
        }
        __syncthreads();

        // Pass C: LDS scatter into run order
        #pragma unroll
        for (int u = 0; u < EPT; ++u) {
            if (dd[u] != 0xFFFFFFFFu) {
                unsigned int pos = offs[bk[u]] + slot[u];
                svals[pos] = pk[u];
                sbid[pos]  = (unsigned short)bk[u];
            }
        }
        __syncthreads();

        // Pass D: linear coalesced write
        for (int j = tid; j < tile_n; j += NTHR) {
            unsigned int bb = sbid[j];
            unsigned int gi = gbase[bb] + ((unsigned int)j - offs[bb]);
            unsigned int lim = bb * (unsigned int)CAP
                             + (unsigned int)(rep + 1) * SUBCAP;
            if (gi < lim)
                sorted_g[gi] = svals[j];
        }
        __syncthreads();   // protect hist/svals reuse across tile iterations
    }
    grid.sync();

    // ================= Phase 3: bucket accum + pool (grid-stride) ==========
    const float* x = (const float*)x4;
    for (int k = bid; k < nb; k += NBLK) {
        __syncthreads();   // protect LDS reuse (sgid/pnum read by wave 0 prev iter)
        int node0 = k * BUCKET_SZ;

        if (tid < BUCKET_SZ) acc[tid] = 0;
        else if (tid < 2 * BUCKET_SZ) {
            int t2 = tid - BUCKET_SZ;
            int node = node0 + t2;
            g_lds[t2] = (node < n_nodes) ? batch[node] : -1;
        }
        if (tid < NREP) {
            unsigned int begr = (unsigned int)(k * CAP + tid * SUBCAP);
            cnts[tid] = min(cursor[tid * nb + k] - begr, (unsigned int)SUBCAP);
        }
        if (tid < NSEG) sgid[tid] = -1;
        __syncthreads();

        // Phase A: 16 waves, 2 per replica
        {
            int rep_id = wid >> 1;
            int sub    = ((wid & 1) << 6) + lane;     // 0..127
            unsigned int beg = (unsigned int)(k * CAP + rep_id * SUBCAP);
            unsigned int cnt = cnts[rep_id];
            unsigned int n4  = cnt & ~3u;
            for (unsigned int j = (unsigned int)sub * 4; j < n4; j += 512) {
                uint4 vv = *(const uint4*)(sorted_g + beg + j);
                atomicAdd(&acc[vv.x & 255u], (int)vv.x >> 8);
                atomicAdd(&acc[vv.y & 255u], (int)vv.y >> 8);
                atomicAdd(&acc[vv.z & 255u], (int)vv.z >> 8);
                atomicAdd(&acc[vv.w & 255u], (int)vv.w >> 8);
            }
            for (unsigned int j = n4 + (unsigned int)sub; j < cnt; j += 128) {
                unsigned int vv = sorted_g[beg + j];
                atomicAdd(&acc[vv & 255u], (int)vv >> 8);
            }
        }
        __syncthreads();

        // Phase B: e = exp(score) in LDS
        if (tid < BUCKET_SZ) {
            int node = node0 + tid;
            e_lds[tid] = (node < n_nodes)
                       ? __expf((float)acc[tid] * INV_PSCALE + r[node]) : 0.0f;
        }
        __syncthreads();

        // Phase C1: 16 waves x 16 rows, batched loads first (R22)
        int l0 = wid * 16;
        int row0 = node0 + l0;
        int s0 = wid * 2;
        if (row0 < n_nodes) {
            int rend = min(row0 + 16, n_nodes);
            int gF = g_lds[l0];
            int gL = g_lds[rend - 1 - node0];
            float sA = 0.0f, sB = 0.0f, zA = 0.0f, zB = 0.0f;

            if (rend - row0 == 16) {
                float xv[16];
                const float* xp = x + (size_t)row0 * H + lane;
                #pragma unroll
                for (int u = 0; u < 16; ++u)
                    xv[u] = xp[u * H];
                #pragma unroll
                for (int u = 0; u < 16; ++u) {
                    int li = l0 + u;
                    int g = g_lds[li];
                    float e = e_lds[li];
                    float vv = xv[u] * e;
                    if (g == gF)      { sA += vv; zA += e; }
                    else if (g == gL) { sB += vv; zB += e; }
                    else {
                        unsafeAtomicAdd(&num[g * H + lane], vv);
                        if (lane == 0) unsafeAtomicAdd(&z[g], e);
                    }
                }
            } else {
                for (int i = row0; i < rend; ++i) {
                    int li = i - node0;
                    int g = g_lds[li];
                    float e = e_lds[li];
                    float vv = x[(size_t)i * H + lane] * e;
                    if (g == gF)      { sA += vv; zA += e; }
                    else if (g == gL) { sB += vv; zB += e; }
                    else {
                        unsafeAtomicAdd(&num[g * H + lane], vv);
                        if (lane == 0) unsafeAtomicAdd(&z[g], e);
                    }
                }
            }
            pnum[s0][lane] = sA;
            if (lane == 0) { sgid[s0] = gF; pz[s0] = zA; }
            if (gL != gF) {
                pnum[s0 + 1][lane] = sB;
                if (lane == 0) { sgid[s0 + 1] = gL; pz[s0 + 1] = zB; }
            }
        }
        __syncthreads();

        // Phase C2: wave 0 merges ordered segments
        if (wid == 0) {
            float run = 0.0f, runz = 0.0f; int cur = -1;
            for (int s = 0; s < NSEG; ++s) {
                int id = sgid[s];
                if (id < 0) continue;
                float vv = pnum[s][lane];
                float zv = pz[s];
                if (id != cur) {
                    if (cur >= 0) {
                        unsafeAtomicAdd(&num[cur * H + lane], run);
                        if (lane == 0) unsafeAtomicAdd(&z[cur], runz);
                    }
                    cur = id; run = vv; runz = zv;
                } else { run += vv; runz += zv; }
            }
            if (cur >= 0) {
                unsafeAtomicAdd(&num[cur * H + lane], run);
                if (lane == 0) unsafeAtomicAdd(&z[cur], runz);
            }
        }
    }
    grid.sync();

    // ================= Phase 4: finalize =================
    if (gt < out_size) {
        float zz = z[gt >> 6];
        out[gt] = (zz != 0.0f) ? num[gt] / zz : 0.0f;
    }
}

extern "C" void kernel_launch(void* const* d_in, const int* in_sizes, int n_in,
                              void* d_out, int out_size, void* d_ws, size_t ws_size,
                              hipStream_t stream)
{
    const float* x      = (const float*)d_in[0];
    const int*   eidx   = (const int*)d_in[1];   // [2, E] int32
    const int*   batch  = (const int*)d_in[2];   // [N] int32, sorted
    const float* W_rel  = (const float*)d_in[3];
    // d_in[4] = b_rel: cancels in softmax
    const float* W_root = (const float*)d_in[5];
    float* out = (float*)d_out;

    const int n_nodes  = in_sizes[0] / H;          // 100000
    const int n_edges  = in_sizes[1] / 2;          // 1600000
    const int n_graphs = out_size / H;             // 512
    const int nb     = (n_nodes + BUCKET_SZ - 1) / BUCKET_SZ;   // 391
    const int ntiles = (n_edges + TILE - 1) / TILE;             // 391

    const int* src = eidx;
    const int* dst = eidx + n_edges;

    // workspace: p[N] r[N] z[G] num[G*H] cursor[nb*NREP] | sorted_g (16B align)
    float* p     = (float*)d_ws;
    float* r     = p + n_nodes;
    float* z     = r + n_nodes;
    float* num   = z + n_graphs;
    unsigned int* cursor = (unsigned int*)(num + out_size);
    uintptr_t raw = (uintptr_t)(cursor + nb * NREP);
    unsigned int* sorted_g = (unsigned int*)((raw + 15) & ~(uintptr_t)15);

    const float4* x4  = (const float4*)x;
    const float4* wr4 = (const float4*)W_rel;
    const float4* wo4 = (const float4*)W_root;
    int nn = n_nodes, ne = n_edges, ng = n_graphs, nbv = nb, nt = ntiles,
        os = out_size;

    void* args[] = {
        (void*)&x4, (void*)&wr4, (void*)&wo4,
        (void*)&src, (void*)&dst, (void*)&batch,
        (void*)&p, (void*)&r, (void*)&z, (void*)&num,
        (void*)&cursor, (void*)&sorted_g, (void*)&out,
        (void*)&nn, (void*)&ne, (void*)&ng, (void*)&nbv, (void*)&nt,
        (void*)&os
    };
    hipLaunchCooperativeKernel((const void*)fused_pipeline,
                               dim3(NBLK), dim3(NTHR), args, 0, stream);
}

// Round 13
// 111.426 us; speedup vs baseline: 3.8760x; 1.9522x over previous
//
#include <hip/hip_runtime.h>
#include <math.h>
#include <stdint.h>

// GlobalAttentionPool: score = segsum_edges(x[src].W_rel)[dst] + x.W_root (+b_rel,
// cancels in softmax); att = per-graph softmax; out = segsum(x*att).
//
// R2: scattered global atomics never coalesce (~18.6G/s) -> minimize COUNT.
// R8: LDS int fixed-point ds_add_u32. R9/R11: staged LDS->linear sort writes.
// R12: 2-barrier scan + int4 loads. R13: cursor replication null.
// R14/R15 (MEASUREMENT): pad-spin attribution (~100MHz, additive):
//     edge_sort ~16, pool ~20, node_prep ~5, finalize ~1; residual ~70-77us
//     = harness re-poison fill (42.5us/256MiB, in-window) + memsets + gaps.
// R16: fused bucket_accum+pool (block-local dep): 125 -> 118.5.
// R17-R20: four pool theories dead. R21 (ABLATION): Phase C == 100% of
//     bucket_pool; Little's law -> <1 outstanding x-load/wave (merged
//     s_waitcnt on interleaved LDS+global serializes loads).
// R22 (WIN): batch 32 x-loads into regs BEFORE LDS reads: 117.6 -> 109.5
//     (bucket_pool 18.5 -> ~10).
// R23 (ABLATION): edge_sort sum-constraint -> Pass A ~7us = its floor
//     (12.8MB poison-cold index streams + 1.6M L2-gather requests);
//     B/C/D ~3us each. No mystery left inside kernels.
// R24 (FAILED, reverted): cooperative mega-fusion -> fused kernel 129.5us
//     alone (VALUBusy 2.8%, FETCH unchanged): grid-stride 391/256 idles
//     half the CUs every phase-round, grid.sync waits on stragglers +
//     device fences; fusion saved ~6us of gaps, cost ~100us of concurrency.
// R25: REVERT to R22 exactly. Ledger: kernels ~32us (each within ~2us of a
//     BW/request floor) + harness ~70-77us. Pre-commit: if ~109.5 repro ->
//     ROOFLINE (controllable share exhausted; remaining cost is the harness
//     reset stream and per-pass memory floors).

#define H 64
#define TILE 4096           // edges per sort tile
#define NTHR_S 1024
#define EPT (TILE / NTHR_S) // 4
#define BUCKET_SZ 256       // nodes per bucket
#define MAX_NB 400          // >= ceil(100000/256) = 391
#define NREP 8              // cursor replicas (== #XCDs)
#define SUBCAP 768          // slots per (bucket, replica); mean ~513
#define CAP (NREP * SUBCAP) // 6144 slots per bucket
#define PSCALE 16384.0f     // 2^14 fixed-point scale
#define INV_PSCALE 6.103515625e-05f

// K1: per-node dots p = x.W_rel, r = x.W_root (4 threads/node, float4 loads);
// zero num[]/z[]; init cursor[rep*nb + k] = k*CAP + rep*SUBCAP.
__global__ __launch_bounds__(256) void node_prep(
    const float4* __restrict__ x4, const float4* __restrict__ W_rel4,
    const float4* __restrict__ W_root4,
    float* __restrict__ p, float* __restrict__ r,
    float* __restrict__ num, float* __restrict__ z,
    unsigned int* __restrict__ cursor,
    int n_nodes, int num_elems, int n_graphs, int nb)
{
    int gid = (int)(blockIdx.x * blockDim.x + threadIdx.x);
    if (gid < num_elems) num[gid] = 0.0f;
    else if (gid < num_elems + n_graphs) z[gid - num_elems] = 0.0f;
    else if (gid < num_elems + n_graphs + nb * NREP) {
        int idx = gid - num_elems - n_graphs;    // == rep*nb + k
        int rep = idx / nb;
        int k   = idx - rep * nb;
        cursor[idx] = (unsigned int)(k * CAP + rep * SUBCAP);
    }

    int node = blockIdx.x * 64 + (threadIdx.x >> 2);
    int q    = threadIdx.x & 3;
    if (node >= n_nodes) return;

    float pv = 0.0f, rv = 0.0f;
    #pragma unroll
    for (int kk = 0; kk < 4; ++kk) {
        float4 v  = x4[node * 16 + kk * 4 + q];
        float4 wr = W_rel4[kk * 4 + q];
        float4 wo = W_root4[kk * 4 + q];
        pv += v.x * wr.x + v.y * wr.y + v.z * wr.z + v.w * wr.w;
        rv += v.x * wo.x + v.y * wo.y + v.z * wo.z + v.w * wo.w;
    }
    pv += __shfl_xor(pv, 1, 64); pv += __shfl_xor(pv, 2, 64);
    rv += __shfl_xor(rv, 1, 64); rv += __shfl_xor(rv, 2, 64);
    if (q == 0) { p[node] = pv; r[node] = rv; }
}

// K2: per-tile bucket partition with staged coalesced writes. 1024 threads.
// Payload = (round(p[src]*2^14) << 8) | (dst & 255).
__global__ __launch_bounds__(NTHR_S) void edge_sort(
    const int* __restrict__ src, const int* __restrict__ dst,
    const float* __restrict__ p,
    unsigned int* __restrict__ cursor, unsigned int* __restrict__ sorted_g,
    int n_edges, int nb)
{
    __shared__ unsigned int hist[MAX_NB];
    __shared__ unsigned int offs[MAX_NB];
    __shared__ unsigned int gbase[MAX_NB];
    __shared__ unsigned int wtot[8];
    __shared__ unsigned int svals[TILE];          // 16 KB payloads
    __shared__ unsigned short sbid[TILE];         // 8 KB bucket ids

    int b = blockIdx.x;
    int rep = b & (NREP - 1);                     // == XCD id (round-robin)
    int base = b * TILE;
    int tile_n = min(TILE, n_edges - base);
    int tid = threadIdx.x;

    if (tid < nb) hist[tid] = 0;
    __syncthreads();

    // ---- Pass A: vectorized loads + count/slot ----
    unsigned int dd[EPT]; int ss[EPT];
    float pv[EPT];
    unsigned int bk[EPT], pk[EPT], slot[EPT];

    int j0 = tid * EPT;                    // 4 consecutive edges per thread
    if (j0 + EPT <= tile_n) {
        int4 s4 = *(const int4*)(src + base + j0);
        int4 d4 = *(const int4*)(dst + base + j0);
        ss[0] = s4.x; ss[1] = s4.y; ss[2] = s4.z; ss[3] = s4.w;
        dd[0] = (unsigned int)d4.x; dd[1] = (unsigned int)d4.y;
        dd[2] = (unsigned int)d4.z; dd[3] = (unsigned int)d4.w;
    } else {
        #pragma unroll
        for (int u = 0; u < EPT; ++u) {
            int j = j0 + u;
            if (j < tile_n) { ss[u] = src[base + j];
                              dd[u] = (unsigned int)dst[base + j]; }
            else dd[u] = 0xFFFFFFFFu;
        }
    }
    #pragma unroll
    for (int u = 0; u < EPT; ++u)          // batched p gathers (ILP)
        if (dd[u] != 0xFFFFFFFFu) pv[u] = p[ss[u]];
    #pragma unroll
    for (int u = 0; u < EPT; ++u) {
        if (dd[u] != 0xFFFFFFFFu) {
            bk[u] = dd[u] >> 8;
            int q = (int)__float2int_rn(pv[u] * PSCALE);
            q = max(-8388607, min(8388607, q));          // 24-bit clamp
            pk[u] = ((unsigned int)q << 8) | (dd[u] & 255u);
            slot[u] = atomicAdd(&hist[bk[u]], 1u);
        }
    }
    __syncthreads();

    // ---- Pass B: 2-barrier scan ----
    int wv = tid >> 6, ln = tid & 63;
    unsigned int v = 0, xs = 0;
    if (wv < 7) {
        int bin = wv * 64 + ln;                    // 0..447 covers nb<=400
        v = (bin < nb) ? hist[bin] : 0;
        xs = v;                                     // inclusive shuffle scan
        #pragma unroll
        for (int off = 1; off < 64; off <<= 1) {
            unsigned int y = __shfl_up(xs, off, 64);
            if (ln >= off) xs += y;
        }
        if (ln == 63) wtot[wv] = xs;
    }
    __syncthreads();
    if (wv < 7) {
        int bin = wv * 64 + ln;
        unsigned int pre = 0;
        #pragma unroll
        for (int w2 = 0; w2 < 7; ++w2)
            pre += (w2 < wv) ? wtot[w2] : 0u;
        if (bin < nb) {
            offs[bin]  = pre + xs - v;             // exclusive prefix
            gbase[bin] = v ? atomicAdd(&cursor[rep * nb + bin], v) : 0u;
        }
    }
    __syncthreads();

    // ---- Pass C: LDS scatter into run order ----
    #pragma unroll
    for (int u = 0; u < EPT; ++u) {
        if (dd[u] != 0xFFFFFFFFu) {
            unsigned int pos = offs[bk[u]] + slot[u];
            svals[pos] = pk[u];
            sbid[pos]  = (unsigned short)bk[u];
        }
    }
    __syncthreads();

    // ---- Pass D: linear write (consecutive j -> consecutive global) ----
    for (int j = tid; j < tile_n; j += NTHR_S) {
        unsigned int bb = sbid[j];
        unsigned int gi = gbase[bb] + ((unsigned int)j - offs[bb]);
        unsigned int lim = bb * (unsigned int)CAP
                         + (unsigned int)(rep + 1) * SUBCAP;
        if (gi < lim)                               // sub-region overflow guard
            sorted_g[gi] = svals[j];
    }
}

// K3 (fused bucket_accum + pool), one 512-thread block per 256-node bucket.
//   Phase A: wave w accumulates replica sub-region w (uint4 + ds_add_u32).
//   Phase B: e_lds = exp(acc*s + r) in LDS.
//   Phase C1 (R22): BATCHED -- 32 pure global x loads into registers first
//     (full unroll, no LDS ops between them -> all 32 in flight), THEN LDS
//     e/g reads + segment accumulation (branches/fallback atomics here).
//   Phase C2: wave 0 merges ordered segments -> one atomic per distinct
//     (graph, lane) per block.
__global__ __launch_bounds__(512) void bucket_pool(
    const unsigned int* __restrict__ sorted_g,
    const unsigned int* __restrict__ cursor,
    const float* __restrict__ r,
    const float* __restrict__ x,
    const int* __restrict__ batch,
    float* __restrict__ num, float* __restrict__ z,
    int n_nodes, int nb)
{
    __shared__ int acc[BUCKET_SZ];
    __shared__ float e_lds[BUCKET_SZ];
    __shared__ int g_lds[BUCKET_SZ];
    __shared__ unsigned int cnts[NREP];
    __shared__ float pnum[2 * NREP][H];           // 4 KB segment partials
    __shared__ float pz[2 * NREP];
    __shared__ int   sgid[2 * NREP];

    int k = blockIdx.x;
    int tid = threadIdx.x;
    int node0 = k * BUCKET_SZ;

    if (tid < BUCKET_SZ) acc[tid] = 0;
    else {
        int t2 = tid - BUCKET_SZ;                 // 0..255
        int node = node0 + t2;
        g_lds[t2] = (node < n_nodes) ? batch[node] : -1;
    }
    if (tid < NREP) {
        unsigned int begr = (unsigned int)(k * CAP + tid * SUBCAP);
        cnts[tid] = min(cursor[tid * nb + k] - begr, (unsigned int)SUBCAP);
    }
    if (tid < 2 * NREP) sgid[tid] = -1;
    __syncthreads();

    // ---- Phase A: wave w accumulates replica w ----
    {
        int wv = tid >> 6, ln = tid & 63;         // wv == replica id
        unsigned int beg = (unsigned int)(k * CAP + wv * SUBCAP);
        unsigned int cnt = cnts[wv];
        unsigned int n4  = cnt & ~3u;
        for (unsigned int j = ln * 4; j < n4; j += 256) {
            uint4 v = *(const uint4*)(sorted_g + beg + j);
            atomicAdd(&acc[v.x & 255u], (int)v.x >> 8);
            atomicAdd(&acc[v.y & 255u], (int)v.y >> 8);
            atomicAdd(&acc[v.z & 255u], (int)v.z >> 8);
            atomicAdd(&acc[v.w & 255u], (int)v.w >> 8);
        }
        for (unsigned int j = n4 + ln; j < cnt; j += 64) {
            unsigned int v = sorted_g[beg + j];
            atomicAdd(&acc[v & 255u], (int)v >> 8);
        }
    }
    __syncthreads();

    // ---- Phase B: e = exp(score) in LDS ----
    if (tid < BUCKET_SZ) {
        int node = node0 + tid;
        e_lds[tid] = (node < n_nodes)
                   ? __expf((float)acc[tid] * INV_PSCALE + r[node]) : 0.0f;
    }
    __syncthreads();

    // ---- Phase C1: batched loads, then accumulate ----
    int wid = tid >> 6, lane = tid & 63;
    int l0 = wid * 32;
    int row0 = node0 + l0;
    int s0 = wid * 2;
    if (row0 < n_nodes) {
        int rend = min(row0 + 32, n_nodes);
        int gF = g_lds[l0];
        int gL = g_lds[rend - 1 - node0];
        float sA = 0.0f, sB = 0.0f, zA = 0.0f, zB = 0.0f;

        if (rend - row0 == 32) {
            // batched path: 32 pure global loads, all in flight
            float xv[32];
            const float* xp = x + (size_t)row0 * H + lane;
            #pragma unroll
            for (int u = 0; u < 32; ++u)
                xv[u] = xp[u * H];
            // accumulate (LDS reads + branches AFTER all loads issued)
            #pragma unroll
            for (int u = 0; u < 32; ++u) {
                int li = l0 + u;
                int g = g_lds[li];                // wave-uniform
                float e = e_lds[li];
                float v = xv[u] * e;
                if (g == gF)      { sA += v; zA += e; }
                else if (g == gL) { sB += v; zB += e; }
                else {                            // graph interior to window
                    unsafeAtomicAdd(&num[g * H + lane], v);
                    if (lane == 0) unsafeAtomicAdd(&z[g], e);
                }
            }
        } else {
            // generic tail path (not hit at N=100000: windows are full)
            for (int i = row0; i < rend; ++i) {
                int li = i - node0;
                int g = g_lds[li];
                float e = e_lds[li];
                float v = x[(size_t)i * H + lane] * e;
                if (g == gF)      { sA += v; zA += e; }
                else if (g == gL) { sB += v; zB += e; }
                else {
                    unsafeAtomicAdd(&num[g * H + lane], v);
                    if (lane == 0) unsafeAtomicAdd(&z[g], e);
                }
            }
        }
        pnum[s0][lane] = sA;
        if (lane == 0) { sgid[s0] = gF; pz[s0] = zA; }
        if (gL != gF) {
            pnum[s0 + 1][lane] = sB;
            if (lane == 0) { sgid[s0 + 1] = gL; pz[s0 + 1] = zB; }
        }
    }
    __syncthreads();

    // ---- Phase C2: wave 0 merges ordered segments -> per-graph atomics ----
    if (wid == 0) {
        float run = 0.0f, runz = 0.0f; int cur = -1;
        for (int s = 0; s < 2 * NREP; ++s) {
            int id = sgid[s];                     // non-decreasing over s
            if (id < 0) continue;
            float v  = pnum[s][lane];
            float zv = pz[s];
            if (id != cur) {
                if (cur >= 0) {
                    unsafeAtomicAdd(&num[cur * H + lane], run);
                    if (lane == 0) unsafeAtomicAdd(&z[cur], runz);
                }
                cur = id; run = v; runz = zv;
            } else { run += v; runz += zv; }
        }
        if (cur >= 0) {
            unsafeAtomicAdd(&num[cur * H + lane], run);
            if (lane == 0) unsafeAtomicAdd(&z[cur], runz);
        }
    }
}

// K4: out = num / z (plain stores; empty graphs -> 0).
__global__ __launch_bounds__(256) void finalize(
    const float* __restrict__ num, const float* __restrict__ z,
    float* __restrict__ out, int num_elems)
{
    int i = (int)(blockIdx.x * blockDim.x + threadIdx.x);
    if (i >= num_elems) return;
    float zz = z[i >> 6];
    out[i] = (zz != 0.0f) ? num[i] / zz : 0.0f;
}

extern "C" void kernel_launch(void* const* d_in, const int* in_sizes, int n_in,
                              void* d_out, int out_size, void* d_ws, size_t ws_size,
                              hipStream_t stream)
{
    const float* x      = (const float*)d_in[0];
    const int*   eidx   = (const int*)d_in[1];   // [2, E] int32
    const int*   batch  = (const int*)d_in[2];   // [N] int32, sorted
    const float* W_rel  = (const float*)d_in[3];
    // d_in[4] = b_rel: cancels in softmax
    const float* W_root = (const float*)d_in[5];
    float* out = (float*)d_out;

    const int n_nodes  = in_sizes[0] / H;          // 100000
    const int n_edges  = in_sizes[1] / 2;          // 1600000
    const int n_graphs = out_size / H;             // 512
    const int nb     = (n_nodes + BUCKET_SZ - 1) / BUCKET_SZ;   // 391
    const int ntiles = (n_edges + TILE - 1) / TILE;             // 391

    const int* src = eidx;
    const int* dst = eidx + n_edges;

    // workspace: p[N] r[N] z[G] num[G*H] cursor[nb*NREP] | sorted_g (16B align)
    float* p     = (float*)d_ws;
    float* r     = p + n_nodes;
    float* z     = r + n_nodes;
    float* num   = z + n_graphs;
    unsigned int* cursor = (unsigned int*)(num + out_size);
    uintptr_t raw = (uintptr_t)(cursor + nb * NREP);
    unsigned int* sorted_g = (unsigned int*)((raw + 15) & ~(uintptr_t)15);

    int np_blocks = (n_nodes + 63) / 64;   // 1563; also covers zero-init range
    node_prep<<<np_blocks, 256, 0, stream>>>(
        (const float4*)x, (const float4*)W_rel, (const float4*)W_root,
        p, r, num, z, cursor, n_nodes, out_size, n_graphs, nb);
    edge_sort<<<ntiles, NTHR_S, 0, stream>>>(src, dst, p, cursor, sorted_g,
                                             n_edges, nb);
    bucket_pool<<<nb, 512, 0, stream>>>(sorted_g, cursor, r, x, batch,
                                        num, z, n_nodes, nb);
    finalize<<<(out_size + 255) / 256, 256, 0, stream>>>(num, z, out, out_size);
}